// Round 2
// baseline (220.603 us; speedup 1.0000x reference)
//
#include <hip/hip_runtime.h>
#include <math.h>

#define BN_SCALE_F 0.99999500003749969f

// x: [N=64][T=300][C=64][V=25] fp32
// pooled: [N*C=4096][T=300]
// kern:   [4096][3]
// la:     [4096][300]

// ---------------- Kernel 1: mean over V ----------------
__global__ __launch_bounds__(256) void pool_kernel(const float* __restrict__ x,
                                                   float* __restrict__ pooled) {
  __shared__ float buf[6400];
  int bid = blockIdx.x;  // 0..4799, each covers 4 consecutive (n,t)
  const float4* src = (const float4*)(x + (size_t)bid * 6400);
  float4* b4 = (float4*)buf;
  for (int i = threadIdx.x; i < 1600; i += 256) b4[i] = src[i];
  __syncthreads();
  int wave = threadIdx.x >> 6;
  int c = threadIdx.x & 63;
  int nt = bid * 4 + wave;
  int n = nt / 300, t = nt - n * 300;
  const float* p = buf + wave * 1600 + c * 25;
  float s = 0.f;
#pragma unroll
  for (int v = 0; v < 25; ++v) s += p[v];
  pooled[((size_t)(n * 64 + c)) * 300 + t] = s * 0.04f;
}

// ---------------- Kernel 2: G branch (fused, register-resident) ----------------
// 8 rows/block, 512 blocks, 320 threads. Thread owns cols j=tid and j=tid+320.
// Row data read as wave-uniform global loads (scalar path); logits accumulated
// in registers and butterfly-reduced; no row/h LDS tiles.
__global__ __launch_bounds__(320) void g_kernel(const float* __restrict__ pooled,
                                                const float* __restrict__ g_w1,  // [600][300]
                                                const float* __restrict__ g_w2,  // [3][600]
                                                float* __restrict__ kern) {      // [4096][3]
  __shared__ float wsum[5][24];
  int r0 = blockIdx.x * 8;
  int tid = threadIdx.x;
  int j1 = tid;
  int j2 = tid + 320;
  bool has2 = (j2 < 600);
  int j2c = has2 ? j2 : j1;
  const float4* w4a = (const float4*)(g_w1 + (size_t)j1 * 300);
  const float4* w4b = (const float4*)(g_w1 + (size_t)j2c * 300);
  const float4* pb = (const float4*)(pooled + (size_t)r0 * 300);  // wave-uniform rows

  float acc1[8], acc2[8];
#pragma unroll
  for (int r = 0; r < 8; ++r) { acc1[r] = 0.f; acc2[r] = 0.f; }

  for (int t4 = 0; t4 < 75; ++t4) {
    float4 wa = w4a[t4];
    float4 wb = w4b[t4];
#pragma unroll
    for (int r = 0; r < 8; ++r) {
      float4 rv = pb[r * 75 + t4];  // uniform -> s_load / broadcast
      acc1[r] = fmaf(rv.x, wa.x, acc1[r]);
      acc1[r] = fmaf(rv.y, wa.y, acc1[r]);
      acc1[r] = fmaf(rv.z, wa.z, acc1[r]);
      acc1[r] = fmaf(rv.w, wa.w, acc1[r]);
      acc2[r] = fmaf(rv.x, wb.x, acc2[r]);
      acc2[r] = fmaf(rv.y, wb.y, acc2[r]);
      acc2[r] = fmaf(rv.z, wb.z, acc2[r]);
      acc2[r] = fmaf(rv.w, wb.w, acc2[r]);
    }
  }

  float w2a0 = g_w2[j1], w2a1 = g_w2[600 + j1], w2a2 = g_w2[1200 + j1];
  float w2b0 = g_w2[j2c], w2b1 = g_w2[600 + j2c], w2b2 = g_w2[1200 + j2c];

  float lacc[24];
#pragma unroll
  for (int r = 0; r < 8; ++r) {
    float h1 = fmaxf(acc1[r] * BN_SCALE_F, 0.f);
    float h2 = has2 ? fmaxf(acc2[r] * BN_SCALE_F, 0.f) : 0.f;
    lacc[r * 3 + 0] = fmaf(h1, w2a0, h2 * w2b0);
    lacc[r * 3 + 1] = fmaf(h1, w2a1, h2 * w2b1);
    lacc[r * 3 + 2] = fmaf(h1, w2a2, h2 * w2b2);
  }

  // butterfly reduce across the 64-lane wave
#pragma unroll
  for (int off = 1; off < 64; off <<= 1) {
#pragma unroll
    for (int i = 0; i < 24; ++i) lacc[i] += __shfl_xor(lacc[i], off, 64);
  }
  int wave = tid >> 6;
  int lane = tid & 63;
  if (lane == 0) {
#pragma unroll
    for (int i = 0; i < 24; ++i) wsum[wave][i] = lacc[i];
  }
  __syncthreads();
  if (wave == 0) {
    float s = 0.f;
    if (lane < 24) {
#pragma unroll
      for (int w = 0; w < 5; ++w) s += wsum[w][lane];
    }
    float a = __shfl(s, lane * 3 + 0, 64);
    float b = __shfl(s, lane * 3 + 1, 64);
    float c = __shfl(s, lane * 3 + 2, 64);
    if (lane < 8) {
      float m = fmaxf(a, fmaxf(b, c));
      float ea = expf(a - m), eb = expf(b - m), ec = expf(c - m);
      float inv = 1.f / (ea + eb + ec);
      size_t o = (size_t)(r0 + lane) * 3;
      kern[o] = ea * inv;
      kern[o + 1] = eb * inv;
      kern[o + 2] = ec * inv;
    }
  }
}

// ---------------- Kernel 3: L branch ----------------
__global__ __launch_bounds__(320) void l_kernel(const float* __restrict__ pooled,
                                                const float* __restrict__ l_w1,  // [16][64][3]
                                                const float* __restrict__ l_w2,  // [64][16]
                                                float* __restrict__ la) {        // [4096][300]
  __shared__ float p[64][304];   // tp in 0..301 valid; t = tp-1; edges zero
  __shared__ float z[16][300];
  __shared__ float w1s[64][48];  // [c][o*3+k]
  int n = blockIdx.x;
  for (int i = threadIdx.x; i < 3072; i += 320) {
    int k = i % 3;
    int c = (i / 3) & 63;
    int o = i / 192;
    w1s[c][o * 3 + k] = l_w1[i];
  }
  for (int i = threadIdx.x; i < 64 * 304; i += 320) {
    int c = i / 304, tp = i - c * 304;
    p[c][tp] = (tp >= 1 && tp <= 300) ? pooled[(size_t)(n * 64 + c) * 300 + (tp - 1)] : 0.f;
  }
  __syncthreads();
  int t = threadIdx.x;
  if (t < 300) {
    float acc[16];
#pragma unroll
    for (int o = 0; o < 16; ++o) acc[o] = 0.f;
    for (int c = 0; c < 64; ++c) {
      float pk[3];
      pk[0] = p[c][t];
      pk[1] = p[c][t + 1];
      pk[2] = p[c][t + 2];
      const float4* wv4 = (const float4*)(&w1s[c][0]);
      float w[48];
#pragma unroll
      for (int q = 0; q < 12; ++q) {
        float4 f = wv4[q];
        w[q * 4] = f.x; w[q * 4 + 1] = f.y; w[q * 4 + 2] = f.z; w[q * 4 + 3] = f.w;
      }
#pragma unroll
      for (int m = 0; m < 48; ++m) acc[m / 3] = fmaf(w[m], pk[m % 3], acc[m / 3]);
    }
#pragma unroll
    for (int o = 0; o < 16; ++o) {
      float v = acc[o] * BN_SCALE_F;
      z[o][t] = v > 0.f ? v : 0.f;
    }
  }
  __syncthreads();
  {
    int c = threadIdx.x / 5;        // 0..63
    int t4b = threadIdx.x - c * 5;  // 0..4
    const float* w2row = l_w2 + c * 16;
    float w2r[16];
#pragma unroll
    for (int o = 0; o < 16; ++o) w2r[o] = w2row[o];
    float* outp = la + ((size_t)(n * 64 + c)) * 300;
    for (int it = 0; it < 15; ++it) {
      int t4 = t4b + it * 5;  // 0..74
      float4 s = {0.f, 0.f, 0.f, 0.f};
#pragma unroll
      for (int o = 0; o < 16; ++o) {
        float4 zv = *(const float4*)(&z[o][t4 * 4]);
        float wo = w2r[o];
        s.x = fmaf(zv.x, wo, s.x);
        s.y = fmaf(zv.y, wo, s.y);
        s.z = fmaf(zv.z, wo, s.z);
        s.w = fmaf(zv.w, wo, s.w);
      }
      float4 r;
      r.x = 1.f / (1.f + expf(-s.x));
      r.y = 1.f / (1.f + expf(-s.y));
      r.z = 1.f / (1.f + expf(-s.z));
      r.w = 1.f / (1.f + expf(-s.w));
      *(float4*)(&outp[t4 * 4]) = r;
    }
  }
}

// ---------------- Kernel 4: final depthwise temporal conv ----------------
__global__ __launch_bounds__(320) void tam_final_kernel(const float* __restrict__ x,
                                                        const float* __restrict__ la,
                                                        const float* __restrict__ kern,
                                                        float* __restrict__ out) {
  int bid = blockIdx.x;
  int n = bid / 20;
  int rem = bid - n * 20;
  int part = rem / 4;  // 0..4 over cv
  int tc = rem & 3;    // 0..3 over t chunks of 75
  int cv = part * 320 + threadIdx.x;  // 0..1599
  int c = cv / 25;
  int t0 = tc * 75;
  size_t xb = (size_t)n * 480000 + cv;
  const float* lap = la + (size_t)(n * 64 + c) * 300;
  const float* kp = kern + (size_t)(n * 64 + c) * 3;
  float k0 = kp[0], k1 = kp[1], k2 = kp[2];
  float am, ac;
  if (t0 > 0)
    am = x[xb + (size_t)(t0 - 1) * 1600] * lap[t0 - 1];
  else
    am = 0.f;
  ac = x[xb + (size_t)t0 * 1600] * lap[t0];
  float* op = out + xb;
#pragma unroll 5
  for (int t = t0; t < t0 + 75; ++t) {
    float an = 0.f;
    if (t + 1 < 300) an = x[xb + (size_t)(t + 1) * 1600] * lap[t + 1];
    op[(size_t)t * 1600] = fmaf(am, k0, fmaf(ac, k1, an * k2));
    am = ac;
    ac = an;
  }
}

extern "C" void kernel_launch(void* const* d_in, const int* in_sizes, int n_in,
                              void* d_out, int out_size, void* d_ws, size_t ws_size,
                              hipStream_t stream) {
  const float* x = (const float*)d_in[0];
  const float* g_w1 = (const float*)d_in[1];
  const float* g_w2 = (const float*)d_in[2];
  const float* l_w1 = (const float*)d_in[3];
  const float* l_w2 = (const float*)d_in[4];
  float* out = (float*)d_out;
  float* ws = (float*)d_ws;
  float* pooled = ws;                    // 4096*300 = 1,228,800 floats
  float* kern = ws + 1228800;            // 4096*3   = 12,288 floats
  float* lact = ws + 1228800 + 12288;    // 4096*300 = 1,228,800 floats

  hipLaunchKernelGGL(pool_kernel, dim3(4800), dim3(256), 0, stream, x, pooled);
  hipLaunchKernelGGL(g_kernel, dim3(512), dim3(320), 0, stream, pooled, g_w1, g_w2, kern);
  hipLaunchKernelGGL(l_kernel, dim3(64), dim3(320), 0, stream, pooled, l_w1, l_w2, lact);
  hipLaunchKernelGGL(tam_final_kernel, dim3(1280), dim3(320), 0, stream, x, lact, kern, out);
}

// Round 3
// 165.112 us; speedup vs baseline: 1.3361x; 1.3361x over previous
//
#include <hip/hip_runtime.h>
#include <math.h>

#define BN_SCALE_F 0.99999500003749969f

// x: [N=64][T=300][C=64][V=25] fp32
// pooled: [N*C=4096][T=300]
// kern:   [4096][3]
// la:     [4096][300]
// W1P:    [75][600][4]  (W1P[k4][j][kk] = g_w1[j][k4*4+kk])  -> coalesced b128 per lane
// lw1r:   [64][48]      (lw1r[c][o*3+k] = l_w1[o][c][k])     -> uniform s_load per c

// ---------------- Kernel 0: weight repack (one-shot prep) ----------------
__global__ __launch_bounds__(256) void prep_kernel(const float* __restrict__ g_w1,
                                                   const float* __restrict__ l_w1,
                                                   float* __restrict__ w1p,
                                                   float* __restrict__ lw1r) {
  int b = blockIdx.x;
  if (b < 50) {
    // transpose tile: j-tile (10) x k-tile (5), tile 64x64
    __shared__ float tile[64][65];
    int tj = b % 10, tk = b / 10;
    int j0 = tj * 64, k0 = tk * 64;
    for (int it = 0; it < 16; ++it) {
      int i = threadIdx.x + it * 256;
      int jj = i >> 6, kk = i & 63;
      int j = j0 + jj, k = k0 + kk;
      tile[jj][kk] = (j < 600 && k < 300) ? g_w1[(size_t)j * 300 + k] : 0.f;
    }
    __syncthreads();
    // out: lanes ordered (j, kkm) so writes are lane-consecutive
    for (int it = 0; it < 16; ++it) {
      int jloc = threadIdx.x >> 2;      // 0..63
      int kkm = threadIdx.x & 3;        // 0..3
      int kloc = it * 4 + kkm;          // 0..63
      int j = j0 + jloc, k = k0 + kloc;
      if (j < 600 && k < 300) {
        w1p[(size_t)(k >> 2) * 2400 + (size_t)j * 4 + (k & 3)] = tile[jloc][kloc];
      }
    }
    __syncthreads();
  } else {
    // repack l_w1 [16][64][3] -> [64][48]
    for (int i = threadIdx.x; i < 3072; i += 256) {
      int o = i / 192;
      int rem = i - o * 192;
      int c = rem / 3;
      int k = rem - c * 3;
      lw1r[c * 48 + o * 3 + k] = l_w1[i];
    }
  }
}

// ---------------- Kernel 1: mean over V ----------------
__global__ __launch_bounds__(256) void pool_kernel(const float* __restrict__ x,
                                                   float* __restrict__ pooled) {
  __shared__ float buf[6400];
  int bid = blockIdx.x;  // 0..4799, each covers 4 consecutive (n,t)
  const float4* src = (const float4*)(x + (size_t)bid * 6400);
  float4* b4 = (float4*)buf;
  for (int i = threadIdx.x; i < 1600; i += 256) b4[i] = src[i];
  __syncthreads();
  int wave = threadIdx.x >> 6;
  int c = threadIdx.x & 63;
  int nt = bid * 4 + wave;
  int n = nt / 300, t = nt - n * 300;
  const float* p = buf + wave * 1600 + c * 25;
  float s = 0.f;
#pragma unroll
  for (int v = 0; v < 25; ++v) s += p[v];
  pooled[((size_t)(n * 64 + c)) * 300 + t] = s * 0.04f;
}

// ---------------- Kernel 2: G branch (register-resident, coalesced weights) ----------------
// 8 rows/block, 512 blocks, 320 threads. Thread owns cols j=tid, j=tid+320.
// Weight loads via W1P are lane-consecutive float4; row data via uniform s_loads.
__global__ __launch_bounds__(320) void g_kernel(const float* __restrict__ pooled,
                                                const float* __restrict__ w1p,   // [75][600][4]
                                                const float* __restrict__ g_w2,  // [3][600]
                                                float* __restrict__ kern) {      // [4096][3]
  __shared__ float wsum[5][24];
  int r0 = blockIdx.x * 8;
  int tid = threadIdx.x;
  int j1 = tid;
  int j2 = tid + 320;
  bool has2 = (j2 < 600);
  int j2c = has2 ? j2 : j1;
  const float4* wp = (const float4*)w1p;                          // [75][600]
  const float4* pb = (const float4*)(pooled + (size_t)r0 * 300);  // uniform rows

  float acc1[8], acc2[8];
#pragma unroll
  for (int r = 0; r < 8; ++r) { acc1[r] = 0.f; acc2[r] = 0.f; }

  for (int k4 = 0; k4 < 75; ++k4) {
    float4 wa = wp[(size_t)k4 * 600 + j1];
    float4 wb = wp[(size_t)k4 * 600 + j2c];
#pragma unroll
    for (int r = 0; r < 8; ++r) {
      float4 rv = pb[r * 75 + k4];  // block-uniform -> scalar path
      acc1[r] = fmaf(rv.x, wa.x, acc1[r]);
      acc1[r] = fmaf(rv.y, wa.y, acc1[r]);
      acc1[r] = fmaf(rv.z, wa.z, acc1[r]);
      acc1[r] = fmaf(rv.w, wa.w, acc1[r]);
      acc2[r] = fmaf(rv.x, wb.x, acc2[r]);
      acc2[r] = fmaf(rv.y, wb.y, acc2[r]);
      acc2[r] = fmaf(rv.z, wb.z, acc2[r]);
      acc2[r] = fmaf(rv.w, wb.w, acc2[r]);
    }
  }

  float w2a0 = g_w2[j1], w2a1 = g_w2[600 + j1], w2a2 = g_w2[1200 + j1];
  float w2b0 = g_w2[j2c], w2b1 = g_w2[600 + j2c], w2b2 = g_w2[1200 + j2c];

  float lacc[24];
#pragma unroll
  for (int r = 0; r < 8; ++r) {
    float h1 = fmaxf(acc1[r] * BN_SCALE_F, 0.f);
    float h2 = has2 ? fmaxf(acc2[r] * BN_SCALE_F, 0.f) : 0.f;
    lacc[r * 3 + 0] = fmaf(h1, w2a0, h2 * w2b0);
    lacc[r * 3 + 1] = fmaf(h1, w2a1, h2 * w2b1);
    lacc[r * 3 + 2] = fmaf(h1, w2a2, h2 * w2b2);
  }

#pragma unroll
  for (int off = 1; off < 64; off <<= 1) {
#pragma unroll
    for (int i = 0; i < 24; ++i) lacc[i] += __shfl_xor(lacc[i], off, 64);
  }
  int wave = tid >> 6;
  int lane = tid & 63;
  if (lane == 0) {
#pragma unroll
    for (int i = 0; i < 24; ++i) wsum[wave][i] = lacc[i];
  }
  __syncthreads();
  if (wave == 0) {
    float s = 0.f;
    if (lane < 24) {
#pragma unroll
      for (int w = 0; w < 5; ++w) s += wsum[w][lane];
    }
    float a = __shfl(s, lane * 3 + 0, 64);
    float b = __shfl(s, lane * 3 + 1, 64);
    float c = __shfl(s, lane * 3 + 2, 64);
    if (lane < 8) {
      float m = fmaxf(a, fmaxf(b, c));
      float ea = expf(a - m), eb = expf(b - m), ec = expf(c - m);
      float inv = 1.f / (ea + eb + ec);
      size_t o = (size_t)(r0 + lane) * 3;
      kern[o] = ea * inv;
      kern[o + 1] = eb * inv;
      kern[o + 2] = ec * inv;
    }
  }
}

// ---------------- Kernel 3: L branch ----------------
__global__ __launch_bounds__(320) void l_kernel(const float* __restrict__ pooled,
                                                const float* __restrict__ lw1r,  // [64][48]
                                                const float* __restrict__ l_w2,  // [64][16]
                                                float* __restrict__ la) {        // [4096][300]
  __shared__ float p[64][304];   // tp in 0..301 valid; t = tp-1; edges zero
  __shared__ float z[16][300];
  int n = blockIdx.x;
  for (int i = threadIdx.x; i < 64 * 304; i += 320) {
    int c = i / 304, tp = i - c * 304;
    p[c][tp] = (tp >= 1 && tp <= 300) ? pooled[(size_t)(n * 64 + c) * 300 + (tp - 1)] : 0.f;
  }
  __syncthreads();
  int t = threadIdx.x;
  if (t < 300) {
    float acc[16];
#pragma unroll
    for (int o = 0; o < 16; ++o) acc[o] = 0.f;
    for (int c = 0; c < 64; ++c) {
      const float* wr = lw1r + c * 48;  // uniform -> s_load into SGPRs
      float pk0 = p[c][t];
      float pk1 = p[c][t + 1];
      float pk2 = p[c][t + 2];
#pragma unroll
      for (int o = 0; o < 16; ++o) {
        acc[o] = fmaf(wr[o * 3 + 0], pk0, acc[o]);
        acc[o] = fmaf(wr[o * 3 + 1], pk1, acc[o]);
        acc[o] = fmaf(wr[o * 3 + 2], pk2, acc[o]);
      }
    }
#pragma unroll
    for (int o = 0; o < 16; ++o) {
      float v = acc[o] * BN_SCALE_F;
      z[o][t] = v > 0.f ? v : 0.f;
    }
  }
  __syncthreads();
  {
    int c = threadIdx.x / 5;        // 0..63
    int t4b = threadIdx.x - c * 5;  // 0..4
    const float* w2row = l_w2 + c * 16;
    float w2r[16];
#pragma unroll
    for (int o = 0; o < 16; ++o) w2r[o] = w2row[o];
    float* outp = la + ((size_t)(n * 64 + c)) * 300;
    for (int it = 0; it < 15; ++it) {
      int t4 = t4b + it * 5;  // 0..74
      float4 s = {0.f, 0.f, 0.f, 0.f};
#pragma unroll
      for (int o = 0; o < 16; ++o) {
        float4 zv = *(const float4*)(&z[o][t4 * 4]);
        float wo = w2r[o];
        s.x = fmaf(zv.x, wo, s.x);
        s.y = fmaf(zv.y, wo, s.y);
        s.z = fmaf(zv.z, wo, s.z);
        s.w = fmaf(zv.w, wo, s.w);
      }
      float4 r;
      r.x = 1.f / (1.f + expf(-s.x));
      r.y = 1.f / (1.f + expf(-s.y));
      r.z = 1.f / (1.f + expf(-s.z));
      r.w = 1.f / (1.f + expf(-s.w));
      *(float4*)(&outp[t4 * 4]) = r;
    }
  }
}

// ---------------- Kernel 4: final depthwise temporal conv ----------------
__global__ __launch_bounds__(320) void tam_final_kernel(const float* __restrict__ x,
                                                        const float* __restrict__ la,
                                                        const float* __restrict__ kern,
                                                        float* __restrict__ out) {
  int bid = blockIdx.x;
  int n = bid / 20;
  int rem = bid - n * 20;
  int part = rem / 4;  // 0..4 over cv
  int tc = rem & 3;    // 0..3 over t chunks of 75
  int cv = part * 320 + threadIdx.x;  // 0..1599
  int c = cv / 25;
  int t0 = tc * 75;
  size_t xb = (size_t)n * 480000 + cv;
  const float* lap = la + (size_t)(n * 64 + c) * 300;
  const float* kp = kern + (size_t)(n * 64 + c) * 3;
  float k0 = kp[0], k1 = kp[1], k2 = kp[2];
  float am, ac;
  if (t0 > 0)
    am = x[xb + (size_t)(t0 - 1) * 1600] * lap[t0 - 1];
  else
    am = 0.f;
  ac = x[xb + (size_t)t0 * 1600] * lap[t0];
  float* op = out + xb;
#pragma unroll 5
  for (int t = t0; t < t0 + 75; ++t) {
    float an = 0.f;
    if (t + 1 < 300) an = x[xb + (size_t)(t + 1) * 1600] * lap[t + 1];
    op[(size_t)t * 1600] = fmaf(am, k0, fmaf(ac, k1, an * k2));
    am = ac;
    ac = an;
  }
}

extern "C" void kernel_launch(void* const* d_in, const int* in_sizes, int n_in,
                              void* d_out, int out_size, void* d_ws, size_t ws_size,
                              hipStream_t stream) {
  const float* x = (const float*)d_in[0];
  const float* g_w1 = (const float*)d_in[1];
  const float* g_w2 = (const float*)d_in[2];
  const float* l_w1 = (const float*)d_in[3];
  const float* l_w2 = (const float*)d_in[4];
  float* out = (float*)d_out;
  float* ws = (float*)d_ws;
  float* pooled = ws;                          // 1,228,800 floats
  float* kern = ws + 1228800;                  // 12,288
  float* lact = ws + 1228800 + 12288;          // 1,228,800
  float* w1p = ws + 1228800 + 12288 + 1228800; // 180,000
  float* lw1r = w1p + 180000;                  // 3,072

  hipLaunchKernelGGL(prep_kernel, dim3(51), dim3(256), 0, stream, g_w1, l_w1, w1p, lw1r);
  hipLaunchKernelGGL(pool_kernel, dim3(4800), dim3(256), 0, stream, x, pooled);
  hipLaunchKernelGGL(g_kernel, dim3(512), dim3(320), 0, stream, pooled, w1p, g_w2, kern);
  hipLaunchKernelGGL(l_kernel, dim3(64), dim3(320), 0, stream, pooled, lw1r, l_w2, lact);
  hipLaunchKernelGGL(tam_final_kernel, dim3(1280), dim3(320), 0, stream, x, lact, kern, out);
}

// Round 4
// 164.827 us; speedup vs baseline: 1.3384x; 1.0017x over previous
//
#include <hip/hip_runtime.h>
#include <math.h>

#define BN_SCALE_F 0.99999500003749969f

// x: [N=64][T=300][C=64][V=25] fp32
// pooled: [N*C=4096][T=300]
// kern:   [4096][3]
// la:     [4096][300]
// W1P:    [75][600][4]  (W1P[k4][j][kk] = g_w1[j][k4*4+kk])  -> coalesced b128 per lane
// lw1r:   [64][48]      (lw1r[c][o*3+k] = l_w1[o][c][k])     -> uniform s_load per c

// ---------------- Kernel 0: weight repack (one-shot prep) ----------------
__global__ __launch_bounds__(256) void prep_kernel(const float* __restrict__ g_w1,
                                                   const float* __restrict__ l_w1,
                                                   float* __restrict__ w1p,
                                                   float* __restrict__ lw1r) {
  int b = blockIdx.x;
  if (b < 50) {
    __shared__ float tile[64][65];
    int tj = b % 10, tk = b / 10;
    int j0 = tj * 64, k0 = tk * 64;
    for (int it = 0; it < 16; ++it) {
      int i = threadIdx.x + it * 256;
      int jj = i >> 6, kk = i & 63;
      int j = j0 + jj, k = k0 + kk;
      tile[jj][kk] = (j < 600 && k < 300) ? g_w1[(size_t)j * 300 + k] : 0.f;
    }
    __syncthreads();
    for (int it = 0; it < 16; ++it) {
      int jloc = threadIdx.x >> 2;
      int kkm = threadIdx.x & 3;
      int kloc = it * 4 + kkm;
      int j = j0 + jloc, k = k0 + kloc;
      if (j < 600 && k < 300) {
        w1p[(size_t)(k >> 2) * 2400 + (size_t)j * 4 + (k & 3)] = tile[jloc][kloc];
      }
    }
    __syncthreads();
  } else {
    for (int i = threadIdx.x; i < 3072; i += 256) {
      int o = i / 192;
      int rem = i - o * 192;
      int c = rem / 3;
      int k = rem - c * 3;
      lw1r[c * 48 + o * 3 + k] = l_w1[i];
    }
  }
}

// ---------------- Kernel 1: mean over V ----------------
__global__ __launch_bounds__(256) void pool_kernel(const float* __restrict__ x,
                                                   float* __restrict__ pooled) {
  __shared__ float buf[6400];
  int bid = blockIdx.x;  // 0..4799, each covers 4 consecutive (n,t)
  const float4* src = (const float4*)(x + (size_t)bid * 6400);
  float4* b4 = (float4*)buf;
  for (int i = threadIdx.x; i < 1600; i += 256) b4[i] = src[i];
  __syncthreads();
  int wave = threadIdx.x >> 6;
  int c = threadIdx.x & 63;
  int nt = bid * 4 + wave;
  int n = nt / 300, t = nt - n * 300;
  const float* p = buf + wave * 1600 + c * 25;
  float s = 0.f;
#pragma unroll
  for (int v = 0; v < 25; ++v) s += p[v];
  pooled[((size_t)(n * 64 + c)) * 300 + t] = s * 0.04f;
}

// ---------------- Kernel 2: G branch (LDS rows + double-buffered weights) ----------------
// 8 rows/block, 512 blocks, 320 threads. Thread owns cols j=tid, j=tid+320.
__global__ __launch_bounds__(320) void g_kernel(const float* __restrict__ pooled,
                                                const float* __restrict__ w1p,   // [75][600][4]
                                                const float* __restrict__ g_w2,  // [3][600]
                                                float* __restrict__ kern) {      // [4096][3]
  __shared__ float rows[8][300];
  __shared__ float wsum[5][24];
  int r0 = blockIdx.x * 8;
  int tid = threadIdx.x;
  {
    const float4* src = (const float4*)(pooled + (size_t)r0 * 300);
    float4* dst = (float4*)&rows[0][0];
    for (int i = tid; i < 600; i += 320) dst[i] = src[i];
  }
  __syncthreads();

  int j1 = tid;
  int j2 = tid + 320;
  bool has2 = (j2 < 600);
  int j2c = has2 ? j2 : j1;
  const float4* wp = (const float4*)w1p;  // [75][600]

  float acc1[8], acc2[8];
#pragma unroll
  for (int r = 0; r < 8; ++r) { acc1[r] = 0.f; acc2[r] = 0.f; }

  float4 wa = wp[j1];
  float4 wb = wp[j2c];
  for (int k4 = 0; k4 < 75; ++k4) {
    float4 wan, wbn;
    if (k4 < 74) {
      wan = wp[(size_t)(k4 + 1) * 600 + j1];
      wbn = wp[(size_t)(k4 + 1) * 600 + j2c];
    } else {
      wan = wa;
      wbn = wb;
    }
#pragma unroll
    for (int r = 0; r < 8; ++r) {
      float4 rv = *(const float4*)(&rows[r][k4 * 4]);  // uniform -> LDS broadcast
      acc1[r] = fmaf(rv.x, wa.x, acc1[r]);
      acc1[r] = fmaf(rv.y, wa.y, acc1[r]);
      acc1[r] = fmaf(rv.z, wa.z, acc1[r]);
      acc1[r] = fmaf(rv.w, wa.w, acc1[r]);
      acc2[r] = fmaf(rv.x, wb.x, acc2[r]);
      acc2[r] = fmaf(rv.y, wb.y, acc2[r]);
      acc2[r] = fmaf(rv.z, wb.z, acc2[r]);
      acc2[r] = fmaf(rv.w, wb.w, acc2[r]);
    }
    wa = wan;
    wb = wbn;
  }

  float w2a0 = g_w2[j1], w2a1 = g_w2[600 + j1], w2a2 = g_w2[1200 + j1];
  float w2b0 = g_w2[j2c], w2b1 = g_w2[600 + j2c], w2b2 = g_w2[1200 + j2c];

  float lacc[24];
#pragma unroll
  for (int r = 0; r < 8; ++r) {
    float h1 = fmaxf(acc1[r] * BN_SCALE_F, 0.f);
    float h2 = has2 ? fmaxf(acc2[r] * BN_SCALE_F, 0.f) : 0.f;
    lacc[r * 3 + 0] = fmaf(h1, w2a0, h2 * w2b0);
    lacc[r * 3 + 1] = fmaf(h1, w2a1, h2 * w2b1);
    lacc[r * 3 + 2] = fmaf(h1, w2a2, h2 * w2b2);
  }

#pragma unroll
  for (int off = 1; off < 64; off <<= 1) {
#pragma unroll
    for (int i = 0; i < 24; ++i) lacc[i] += __shfl_xor(lacc[i], off, 64);
  }
  int wave = tid >> 6;
  int lane = tid & 63;
  if (lane == 0) {
#pragma unroll
    for (int i = 0; i < 24; ++i) wsum[wave][i] = lacc[i];
  }
  __syncthreads();
  if (wave == 0) {
    float s = 0.f;
    if (lane < 24) {
#pragma unroll
      for (int w = 0; w < 5; ++w) s += wsum[w][lane];
    }
    float a = __shfl(s, lane * 3 + 0, 64);
    float b = __shfl(s, lane * 3 + 1, 64);
    float c = __shfl(s, lane * 3 + 2, 64);
    if (lane < 8) {
      float m = fmaxf(a, fmaxf(b, c));
      float ea = expf(a - m), eb = expf(b - m), ec = expf(c - m);
      float inv = 1.f / (ea + eb + ec);
      size_t o = (size_t)(r0 + lane) * 3;
      kern[o] = ea * inv;
      kern[o + 1] = eb * inv;
      kern[o + 2] = ec * inv;
    }
  }
}

// ---------------- Kernel 3: L branch ----------------
__global__ __launch_bounds__(320) void l_kernel(const float* __restrict__ pooled,
                                                const float* __restrict__ lw1r,  // [64][48]
                                                const float* __restrict__ l_w2,  // [64][16]
                                                float* __restrict__ la) {        // [4096][300]
  __shared__ float p[64][304];
  __shared__ float z[16][300];
  int n = blockIdx.x;
  for (int i = threadIdx.x; i < 64 * 304; i += 320) {
    int c = i / 304, tp = i - c * 304;
    p[c][tp] = (tp >= 1 && tp <= 300) ? pooled[(size_t)(n * 64 + c) * 300 + (tp - 1)] : 0.f;
  }
  __syncthreads();
  int t = threadIdx.x;
  if (t < 300) {
    float acc[16];
#pragma unroll
    for (int o = 0; o < 16; ++o) acc[o] = 0.f;
    for (int c = 0; c < 64; ++c) {
      const float* wr = lw1r + c * 48;  // uniform -> s_load into SGPRs
      float pk0 = p[c][t];
      float pk1 = p[c][t + 1];
      float pk2 = p[c][t + 2];
#pragma unroll
      for (int o = 0; o < 16; ++o) {
        acc[o] = fmaf(wr[o * 3 + 0], pk0, acc[o]);
        acc[o] = fmaf(wr[o * 3 + 1], pk1, acc[o]);
        acc[o] = fmaf(wr[o * 3 + 2], pk2, acc[o]);
      }
    }
#pragma unroll
    for (int o = 0; o < 16; ++o) {
      float v = acc[o] * BN_SCALE_F;
      z[o][t] = v > 0.f ? v : 0.f;
    }
  }
  __syncthreads();
  {
    int c = threadIdx.x / 5;
    int t4b = threadIdx.x - c * 5;
    const float* w2row = l_w2 + c * 16;
    float w2r[16];
#pragma unroll
    for (int o = 0; o < 16; ++o) w2r[o] = w2row[o];
    float* outp = la + ((size_t)(n * 64 + c)) * 300;
    for (int it = 0; it < 15; ++it) {
      int t4 = t4b + it * 5;
      float4 s = {0.f, 0.f, 0.f, 0.f};
#pragma unroll
      for (int o = 0; o < 16; ++o) {
        float4 zv = *(const float4*)(&z[o][t4 * 4]);
        float wo = w2r[o];
        s.x = fmaf(zv.x, wo, s.x);
        s.y = fmaf(zv.y, wo, s.y);
        s.z = fmaf(zv.z, wo, s.z);
        s.w = fmaf(zv.w, wo, s.w);
      }
      float4 r;
      r.x = 1.f / (1.f + expf(-s.x));
      r.y = 1.f / (1.f + expf(-s.y));
      r.z = 1.f / (1.f + expf(-s.z));
      r.w = 1.f / (1.f + expf(-s.w));
      *(float4*)(&outp[t4 * 4]) = r;
    }
  }
}

// ---------------- Kernel 4: final depthwise temporal conv (float4 columns) ----------------
// Each thread owns one float4 column (4 consecutive (c,v) elems; may straddle one c boundary)
// and slides over a 38-long t chunk. Per-element k/la selected via precomputed masks.
__global__ __launch_bounds__(256) void tam_final_kernel(const float* __restrict__ x,
                                                        const float* __restrict__ la,
                                                        const float* __restrict__ kern,
                                                        float* __restrict__ out) {
  int bid = blockIdx.x;  // 64 n * 8 tchunk * 2 half
  int n = bid >> 4;
  int rem = bid & 15;
  int tch = rem >> 1;
  int half = rem & 1;
  int cv4 = half * 256 + threadIdx.x;
  if (cv4 >= 400) return;
  int e0 = cv4 * 4;
  int c0 = e0 / 25;
  int c3 = (e0 + 3) / 25;
  bool s1 = ((e0 + 1) / 25) != c0;
  bool s2 = ((e0 + 2) / 25) != c0;
  bool s3 = (c3 != c0);
  const float* lap0 = la + (size_t)(n * 64 + c0) * 300;
  const float* lap1 = la + (size_t)(n * 64 + c3) * 300;
  const float* kp0 = kern + (size_t)(n * 64 + c0) * 3;
  const float* kp1 = kern + (size_t)(n * 64 + c3) * 3;
  float k00 = kp0[0], k01 = kp0[1], k02 = kp0[2];
  float k10 = kp1[0], k11 = kp1[1], k12 = kp1[2];
  float4 K0 = {k00, s1 ? k10 : k00, s2 ? k10 : k00, s3 ? k10 : k00};
  float4 K1 = {k01, s1 ? k11 : k01, s2 ? k11 : k01, s3 ? k11 : k01};
  float4 K2 = {k02, s1 ? k12 : k02, s2 ? k12 : k02, s3 ? k12 : k02};

  const float4* xp = (const float4*)(x + (size_t)n * 480000) + cv4;  // +t*400
  float4* op = (float4*)(out + (size_t)n * 480000) + cv4;

  int t0 = tch * 38;
  int tend = t0 + 38;
  if (tend > 300) tend = 300;

#define LAMUL(dst, t)                                        \
  {                                                          \
    float l0 = lap0[(t)];                                    \
    float l1 = lap1[(t)];                                    \
    float4 xv = xp[(size_t)(t) * 400];                       \
    dst.x = xv.x * l0;                                       \
    dst.y = xv.y * (s1 ? l1 : l0);                           \
    dst.z = xv.z * (s2 ? l1 : l0);                           \
    dst.w = xv.w * (s3 ? l1 : l0);                           \
  }

  float4 am, ac, an;
  if (t0 > 0) {
    LAMUL(am, t0 - 1);
  } else {
    am = {0.f, 0.f, 0.f, 0.f};
  }
  LAMUL(ac, t0);
  for (int t = t0; t < tend; ++t) {
    if (t + 1 < 300) {
      LAMUL(an, t + 1);
    } else {
      an = {0.f, 0.f, 0.f, 0.f};
    }
    float4 o;
    o.x = fmaf(am.x, K0.x, fmaf(ac.x, K1.x, an.x * K2.x));
    o.y = fmaf(am.y, K0.y, fmaf(ac.y, K1.y, an.y * K2.y));
    o.z = fmaf(am.z, K0.z, fmaf(ac.z, K1.z, an.z * K2.z));
    o.w = fmaf(am.w, K0.w, fmaf(ac.w, K1.w, an.w * K2.w));
    op[(size_t)t * 400] = o;
    am = ac;
    ac = an;
  }
#undef LAMUL
}

extern "C" void kernel_launch(void* const* d_in, const int* in_sizes, int n_in,
                              void* d_out, int out_size, void* d_ws, size_t ws_size,
                              hipStream_t stream) {
  const float* x = (const float*)d_in[0];
  const float* g_w1 = (const float*)d_in[1];
  const float* g_w2 = (const float*)d_in[2];
  const float* l_w1 = (const float*)d_in[3];
  const float* l_w2 = (const float*)d_in[4];
  float* out = (float*)d_out;
  float* ws = (float*)d_ws;
  float* pooled = ws;                           // 1,228,800 floats
  float* kern = ws + 1228800;                   // 12,288
  float* lact = ws + 1228800 + 12288;           // 1,228,800
  float* w1p = ws + 1228800 + 12288 + 1228800;  // 180,000
  float* lw1r = w1p + 180000;                   // 3,072

  hipLaunchKernelGGL(prep_kernel, dim3(51), dim3(256), 0, stream, g_w1, l_w1, w1p, lw1r);
  hipLaunchKernelGGL(pool_kernel, dim3(4800), dim3(256), 0, stream, x, pooled);
  hipLaunchKernelGGL(g_kernel, dim3(512), dim3(320), 0, stream, pooled, w1p, g_w2, kern);
  hipLaunchKernelGGL(l_kernel, dim3(64), dim3(320), 0, stream, pooled, lw1r, l_w2, lact);
  hipLaunchKernelGGL(tam_final_kernel, dim3(1024), dim3(256), 0, stream, x, lact, kern, out);
}